// Round 1
// baseline (231.852 us; speedup 1.0000x reference)
//
#include <hip/hip_runtime.h>
#include <hip/hip_bf16.h>

// Problem constants (fixed by reference)
constexpr int V_    = 2562;
constexpr int DEG_  = 8;
constexpr int FIN_  = 8;
constexpr int FOUT_ = 16;
constexpr int S_    = 512;              // X*Y*Z
constexpr int VS_   = V_ * S_;          // elements per f-plane of in/out
constexpr int VP_   = 2564;             // V padded to %4==0 (16B-aligned rows)
constexpr int LSTR  = 12;               // LDS floats per vertex (8 used + 4 pad)
constexpr long INT_PLANE = (long)S_ * VP_;   // floats per f-plane of inT
constexpr int TPB   = 1024;
constexpr int NV    = 3;                // vertices per thread (ceil(2562/1024))

__device__ __forceinline__ float4 ld4(const float* p) {
    return *reinterpret_cast<const float4*>(p);
}
__device__ __forceinline__ void st4(float* p, float4 v) {
    *reinterpret_cast<float4*>(p) = v;
}

// ---------------------------------------------------------------------------
// T1: tiled transpose in[f][v][s] -> inT[f][s][v-padded]
// ---------------------------------------------------------------------------
__global__ __launch_bounds__(256)
void transpose_k(const float* __restrict__ src, float* __restrict__ dst,
                 int M, int N, long srcZ, long dstZ, int dstStride)
{
    __shared__ float tile[64][65];
    const long zs = (long)blockIdx.z * srcZ;
    const long zd = (long)blockIdx.z * dstZ;
    const int n0 = blockIdx.x * 64;
    const int m0 = blockIdx.y * 64;
    const int t  = threadIdx.x;
    const int q  = t & 15;
    const int r  = t >> 4;

#pragma unroll
    for (int i = 0; i < 4; ++i) {
        const int m = m0 + r + i * 16;
        const int n = n0 + q * 4;
        if (m < M && n < N) {
            const float4 x = ld4(src + zs + (long)m * N + n);
            tile[r + i * 16][q * 4 + 0] = x.x;
            tile[r + i * 16][q * 4 + 1] = x.y;
            tile[r + i * 16][q * 4 + 2] = x.z;
            tile[r + i * 16][q * 4 + 3] = x.w;
        }
    }
    __syncthreads();
#pragma unroll
    for (int i = 0; i < 4; ++i) {
        const int n = n0 + r + i * 16;
        const int m = m0 + q * 4;
        if (n < N && (m + 4) <= dstStride) {
            const float4 x = make_float4(tile[q * 4 + 0][r + i * 16],
                                         tile[q * 4 + 1][r + i * 16],
                                         tile[q * 4 + 2][r + i * 16],
                                         tile[q * 4 + 3][r + i * 16]);
            st4(dst + zd + (long)n * dstStride + m, x);
        }
    }
}

// ---------------------------------------------------------------------------
// cheb_rec: per s-slice, run the K=5 recursion in LDS (fp32) and emit
// x1..x4 as bf16 to cheb[(k-1)][s][f][v]. No output accumulators ->
// per-thread state ~60 regs, fits the 64-VGPR budget the backend pins.
// ---------------------------------------------------------------------------
__global__ __launch_bounds__(TPB)
void cheb_rec(const float* __restrict__ inT,   // [FIN][S][VP]
              const int*   __restrict__ cols,  // [V][8]
              const float* __restrict__ vals,  // [V][8]
              __hip_bfloat16* __restrict__ cheb) // [4][S][FIN][VP] bf16
{
    extern __shared__ float cur[];              // VP_*LSTR floats = 123072 B
    const int s = blockIdx.x;
    const int t = threadIdx.x;

    // fill cur[v*12 + f] = inT[f][s][v]
    {
        const int f = t & 7;
        const int cb = t >> 3;
        const float* plane = inT + (long)f * INT_PLANE + (long)s * VP_;
        for (int c = cb; c < VP_ / 4; c += TPB / 8) {
            const float4 x = ld4(plane + c * 4);
            cur[(c * 4 + 0) * LSTR + f] = x.x;
            cur[(c * 4 + 1) * LSTR + f] = x.y;
            cur[(c * 4 + 2) * LSTR + f] = x.z;
            cur[(c * 4 + 3) * LSTR + f] = x.w;
        }
    }
    __syncthreads();

    float xp[NV][8];        // x_{k-2} at own vertices (starts as x0)
#pragma unroll
    for (int j = 0; j < NV; ++j) {
        const int v = (t + j * TPB < V_) ? (t + j * TPB) : 0;
        const float4 lo = ld4(&cur[v * LSTR]);
        const float4 hi = ld4(&cur[v * LSTR + 4]);
        xp[j][0] = lo.x; xp[j][1] = lo.y; xp[j][2] = lo.z; xp[j][3] = lo.w;
        xp[j][4] = hi.x; xp[j][5] = hi.y; xp[j][6] = hi.z; xp[j][7] = hi.w;
    }

#pragma unroll 1
    for (int k = 1; k < 5; ++k) {
        float xk[NV][8];
#pragma unroll
        for (int j = 0; j < NV; ++j) {
            const bool valid = (t + j * TPB) < V_;
            const int v = valid ? (t + j * TPB) : 0;
            int off = v * 8;
            asm volatile("" : "+v"(off));       // block LICM of k-invariant loads
            const int4   ca = *reinterpret_cast<const int4*>(cols + off);
            const int4   cb = *reinterpret_cast<const int4*>(cols + off + 4);
            const float4 wa = ld4(vals + off);
            const float4 wb = ld4(vals + off + 4);
            const int   cc[8] = {ca.x, ca.y, ca.z, ca.w, cb.x, cb.y, cb.z, cb.w};
            const float ww[8] = {wa.x, wa.y, wa.z, wa.w, wb.x, wb.y, wb.z, wb.w};

            float a[8];
#pragma unroll
            for (int e = 0; e < 8; ++e) a[e] = 0.f;
#pragma unroll
            for (int n = 0; n < 8; ++n) {
                const float* p = &cur[cc[n] * LSTR];
                const float4 lo = ld4(p);
                const float4 hi = ld4(p + 4);
                const float w = ww[n];
                a[0] = fmaf(w, lo.x, a[0]); a[1] = fmaf(w, lo.y, a[1]);
                a[2] = fmaf(w, lo.z, a[2]); a[3] = fmaf(w, lo.w, a[3]);
                a[4] = fmaf(w, hi.x, a[4]); a[5] = fmaf(w, hi.y, a[5]);
                a[6] = fmaf(w, hi.z, a[6]); a[7] = fmaf(w, hi.w, a[7]);
            }
#pragma unroll
            for (int e = 0; e < 8; ++e)
                xk[j][e] = (k == 1) ? a[e] : fmaf(2.f, a[e], -xp[j][e]);

            // emit bf16 copy for the projection kernel (one rounding only;
            // the fp32 recursion state stays in LDS)
            if (valid) {
                const long pb = ((long)(k - 1) * S_ + s) * FIN_;
#pragma unroll
                for (int f = 0; f < 8; ++f)
                    cheb[(pb + f) * VP_ + v] = __float2bfloat16(xk[j][f]);
            }

            // stage next xprev = x_{k-1}[own] (cur is stable until the barrier)
            if (k < 4) {
                const float4 lo = ld4(&cur[v * LSTR]);
                const float4 hi = ld4(&cur[v * LSTR + 4]);
                xp[j][0] = lo.x; xp[j][1] = lo.y; xp[j][2] = lo.z; xp[j][3] = lo.w;
                xp[j][4] = hi.x; xp[j][5] = hi.y; xp[j][6] = hi.z; xp[j][7] = hi.w;
            }
        }
        if (k < 4) {
            __syncthreads();
#pragma unroll
            for (int j = 0; j < NV; ++j) {
                const int vr = t + j * TPB;
                if (vr < V_) {
                    st4(&cur[vr * LSTR],
                        make_float4(xk[j][0], xk[j][1], xk[j][2], xk[j][3]));
                    st4(&cur[vr * LSTR + 4],
                        make_float4(xk[j][4], xk[j][5], xk[j][6], xk[j][7]));
                }
            }
            __syncthreads();
        }
    }
}

// ---------------------------------------------------------------------------
// proj: out[o][v][s] = bias[o] + sum_{k,f} W[k,f,o] * x_k[f,v,s]
// Block = 64v x 16s tile, 1024 threads, acc[16]/thread (~30 regs).
// x0 staged from the original `in` (s-fast); cheb read v-fast (bf16,
// coalesced); output LDS-transposed per o so stores are s-contiguous.
// ---------------------------------------------------------------------------
__global__ __launch_bounds__(TPB)
void proj(const float* __restrict__ in,          // [FIN][V][S]
          const __hip_bfloat16* __restrict__ cheb, // [4][S][FIN][VP]
          const float* __restrict__ W,           // [5][8][16]
          const float* __restrict__ bias,        // [16]
          float* __restrict__ out)               // [FOUT][V][S]
{
    __shared__ float x0t[FIN_][64][17];
    __shared__ float ot[64][17];
    const int v0 = blockIdx.x * 64;
    const int s0 = blockIdx.y * 16;
    const int t  = threadIdx.x;

    // stage x0 tile (s-fast lanes: 16 consecutive s per v -> dense sectors)
    {
        const int sv = t & 15;
        const int vv = t >> 4;                   // 0..63
        const int vg = (v0 + vv < V_) ? (v0 + vv) : (V_ - 1);
#pragma unroll
        for (int f = 0; f < FIN_; ++f)
            x0t[f][vv][sv] = in[(long)f * VS_ + (long)vg * S_ + s0 + sv];
    }
    __syncthreads();

    const int tv = t & 63;                       // v within tile (v-fast)
    const int ts = t >> 6;                       // s within tile, 0..15
    const int vg = (v0 + tv < V_) ? (v0 + tv) : (V_ - 1);

    float acc[16];
#pragma unroll
    for (int o = 0; o < 16; ++o) acc[o] = bias[o];

    // k = 0 from LDS
#pragma unroll
    for (int f = 0; f < FIN_; ++f) {
        const float xv = x0t[f][tv][ts];
#pragma unroll
        for (int o = 0; o < 16; ++o)
            acc[o] = fmaf(W[f * 16 + o], xv, acc[o]);
    }
    // k = 1..4 from cheb (bf16, lanes consecutive v -> 128B/wave)
#pragma unroll
    for (int k = 1; k < 5; ++k) {
#pragma unroll
        for (int f = 0; f < FIN_; ++f) {
            const long pb = ((long)(k - 1) * S_ + (s0 + ts)) * FIN_ + f;
            const float xv = __bfloat162float(cheb[pb * VP_ + vg]);
#pragma unroll
            for (int o = 0; o < 16; ++o)
                acc[o] = fmaf(W[(k * 8 + f) * 16 + o], xv, acc[o]);
        }
    }

    // write out: LDS-transpose each o-tile so stores are s-contiguous
    const int sv = t & 15;
    const int vv = t >> 4;
    const bool wval = (v0 + vv) < V_;
#pragma unroll 1
    for (int o = 0; o < 16; ++o) {
        __syncthreads();
        ot[tv][ts] = acc[o];
        __syncthreads();
        if (wval)
            out[(long)o * VS_ + (long)(v0 + vv) * S_ + s0 + sv] = ot[vv][sv];
    }
}

extern "C" void kernel_launch(void* const* d_in, const int* in_sizes, int n_in,
                              void* d_out, int out_size, void* d_ws, size_t ws_size,
                              hipStream_t stream) {
    const float* in   = (const float*)d_in[0];
    // d_in[1] = lap_rows == repeat(arange(V), DEG) by construction -> implicit
    const int*   cols = (const int*)d_in[2];
    const float* vals = (const float*)d_in[3];
    const float* W    = (const float*)d_in[4];
    const float* bias = (const float*)d_in[5];
    float* out = (float*)d_out;

    // inT (42 MB) borrows d_out's lower half (only read by cheb_rec, which
    // completes before proj overwrites d_out). cheb bf16 (84.0 MB) in d_ws.
    float* inT = out;
    __hip_bfloat16* cheb = (__hip_bfloat16*)d_ws;

    (void)hipFuncSetAttribute((const void*)cheb_rec,
                              hipFuncAttributeMaxDynamicSharedMemorySize,
                              VP_ * LSTR * (int)sizeof(float));

    // T1: in[f][v][s] -> inT[f][s][v]
    transpose_k<<<dim3(8, 41, 8), 256, 0, stream>>>(
        in, inT, V_, S_, (long)VS_, INT_PLANE, VP_);

    // Recursion: emit x1..x4 (bf16) to cheb
    cheb_rec<<<dim3(S_), TPB, VP_ * LSTR * (int)sizeof(float), stream>>>(
        inT, cols, vals, cheb);

    // Projection + transpose: write final out[o][v][s]
    proj<<<dim3(41, 32), TPB, 0, stream>>>(in, cheb, W, bias, out);
}

// Round 2
// 221.472 us; speedup vs baseline: 1.0469x; 1.0469x over previous
//
#include <hip/hip_runtime.h>
#include <hip/hip_bf16.h>

// Problem constants (fixed by reference)
constexpr int V_    = 2562;
constexpr int DEG_  = 8;
constexpr int FIN_  = 8;
constexpr int FOUT_ = 16;
constexpr int S_    = 512;              // X*Y*Z
constexpr int VS_   = V_ * S_;          // elements per f-plane of in/out
constexpr int VP_   = 2564;             // V padded to %4==0 (16B-aligned rows)
constexpr int LSTR  = 12;               // LDS floats per vertex (8 used + 4 pad)
constexpr long INT_PLANE = (long)S_ * VP_;   // floats per f-plane of inT
constexpr int TPB   = 1024;
constexpr int NV    = 3;                // vertices per thread (ceil(2562/1024))

__device__ __forceinline__ float4 ld4(const float* p) {
    return *reinterpret_cast<const float4*>(p);
}
__device__ __forceinline__ void st4(float* p, float4 v) {
    *reinterpret_cast<float4*>(p) = v;
}

// ---------------------------------------------------------------------------
// T1: tiled transpose in[f][v][s] -> inT[f][s][v-padded]
// ---------------------------------------------------------------------------
__global__ __launch_bounds__(256)
void transpose_k(const float* __restrict__ src, float* __restrict__ dst,
                 int M, int N, long srcZ, long dstZ, int dstStride)
{
    __shared__ float tile[64][65];
    const long zs = (long)blockIdx.z * srcZ;
    const long zd = (long)blockIdx.z * dstZ;
    const int n0 = blockIdx.x * 64;
    const int m0 = blockIdx.y * 64;
    const int t  = threadIdx.x;
    const int q  = t & 15;
    const int r  = t >> 4;

#pragma unroll
    for (int i = 0; i < 4; ++i) {
        const int m = m0 + r + i * 16;
        const int n = n0 + q * 4;
        if (m < M && n < N) {
            const float4 x = ld4(src + zs + (long)m * N + n);
            tile[r + i * 16][q * 4 + 0] = x.x;
            tile[r + i * 16][q * 4 + 1] = x.y;
            tile[r + i * 16][q * 4 + 2] = x.z;
            tile[r + i * 16][q * 4 + 3] = x.w;
        }
    }
    __syncthreads();
#pragma unroll
    for (int i = 0; i < 4; ++i) {
        const int n = n0 + r + i * 16;
        const int m = m0 + q * 4;
        if (n < N && (m + 4) <= dstStride) {
            const float4 x = make_float4(tile[q * 4 + 0][r + i * 16],
                                         tile[q * 4 + 1][r + i * 16],
                                         tile[q * 4 + 2][r + i * 16],
                                         tile[q * 4 + 3][r + i * 16]);
            st4(dst + zd + (long)n * dstStride + m, x);
        }
    }
}

// ---------------------------------------------------------------------------
// cheb_rec: per s-slice, run the K=5 recursion in LDS (fp32) and emit
// x1..x4 as bf16 to cheb[(k-1)][s][f][v]. No output accumulators ->
// per-thread state ~60 regs, fits the 64-VGPR budget the backend pins.
// ---------------------------------------------------------------------------
__global__ __launch_bounds__(TPB)
void cheb_rec(const float* __restrict__ inT,   // [FIN][S][VP]
              const int*   __restrict__ cols,  // [V][8]
              const float* __restrict__ vals,  // [V][8]
              __hip_bfloat16* __restrict__ cheb) // [4][S][FIN][VP] bf16
{
    extern __shared__ float cur[];              // VP_*LSTR floats = 123072 B
    const int s = blockIdx.x;
    const int t = threadIdx.x;

    // fill cur[v*12 + f] = inT[f][s][v]
    {
        const int f = t & 7;
        const int cb = t >> 3;
        const float* plane = inT + (long)f * INT_PLANE + (long)s * VP_;
        for (int c = cb; c < VP_ / 4; c += TPB / 8) {
            const float4 x = ld4(plane + c * 4);
            cur[(c * 4 + 0) * LSTR + f] = x.x;
            cur[(c * 4 + 1) * LSTR + f] = x.y;
            cur[(c * 4 + 2) * LSTR + f] = x.z;
            cur[(c * 4 + 3) * LSTR + f] = x.w;
        }
    }
    __syncthreads();

    float xp[NV][8];        // x_{k-2} at own vertices (starts as x0)
#pragma unroll
    for (int j = 0; j < NV; ++j) {
        const int v = (t + j * TPB < V_) ? (t + j * TPB) : 0;
        const float4 lo = ld4(&cur[v * LSTR]);
        const float4 hi = ld4(&cur[v * LSTR + 4]);
        xp[j][0] = lo.x; xp[j][1] = lo.y; xp[j][2] = lo.z; xp[j][3] = lo.w;
        xp[j][4] = hi.x; xp[j][5] = hi.y; xp[j][6] = hi.z; xp[j][7] = hi.w;
    }

#pragma unroll 1
    for (int k = 1; k < 5; ++k) {
        float xk[NV][8];
#pragma unroll
        for (int j = 0; j < NV; ++j) {
            const bool valid = (t + j * TPB) < V_;
            const int v = valid ? (t + j * TPB) : 0;
            int off = v * 8;
            asm volatile("" : "+v"(off));       // block LICM of k-invariant loads
            const int4   ca = *reinterpret_cast<const int4*>(cols + off);
            const int4   cb = *reinterpret_cast<const int4*>(cols + off + 4);
            const float4 wa = ld4(vals + off);
            const float4 wb = ld4(vals + off + 4);
            const int   cc[8] = {ca.x, ca.y, ca.z, ca.w, cb.x, cb.y, cb.z, cb.w};
            const float ww[8] = {wa.x, wa.y, wa.z, wa.w, wb.x, wb.y, wb.z, wb.w};

            float a[8];
#pragma unroll
            for (int e = 0; e < 8; ++e) a[e] = 0.f;
#pragma unroll
            for (int n = 0; n < 8; ++n) {
                const float* p = &cur[cc[n] * LSTR];
                const float4 lo = ld4(p);
                const float4 hi = ld4(p + 4);
                const float w = ww[n];
                a[0] = fmaf(w, lo.x, a[0]); a[1] = fmaf(w, lo.y, a[1]);
                a[2] = fmaf(w, lo.z, a[2]); a[3] = fmaf(w, lo.w, a[3]);
                a[4] = fmaf(w, hi.x, a[4]); a[5] = fmaf(w, hi.y, a[5]);
                a[6] = fmaf(w, hi.z, a[6]); a[7] = fmaf(w, hi.w, a[7]);
            }
#pragma unroll
            for (int e = 0; e < 8; ++e)
                xk[j][e] = (k == 1) ? a[e] : fmaf(2.f, a[e], -xp[j][e]);

            // emit bf16 copy for the projection kernel (one rounding only;
            // the fp32 recursion state stays in LDS)
            if (valid) {
                const long pb = ((long)(k - 1) * S_ + s) * FIN_;
#pragma unroll
                for (int f = 0; f < 8; ++f)
                    cheb[(pb + f) * VP_ + v] = __float2bfloat16(xk[j][f]);
            }

            // stage next xprev = x_{k-1}[own] (cur is stable until the barrier)
            if (k < 4) {
                const float4 lo = ld4(&cur[v * LSTR]);
                const float4 hi = ld4(&cur[v * LSTR + 4]);
                xp[j][0] = lo.x; xp[j][1] = lo.y; xp[j][2] = lo.z; xp[j][3] = lo.w;
                xp[j][4] = hi.x; xp[j][5] = hi.y; xp[j][6] = hi.z; xp[j][7] = hi.w;
            }
        }
        if (k < 4) {
            __syncthreads();
#pragma unroll
            for (int j = 0; j < NV; ++j) {
                const int vr = t + j * TPB;
                if (vr < V_) {
                    st4(&cur[vr * LSTR],
                        make_float4(xk[j][0], xk[j][1], xk[j][2], xk[j][3]));
                    st4(&cur[vr * LSTR + 4],
                        make_float4(xk[j][4], xk[j][5], xk[j][6], xk[j][7]));
                }
            }
            __syncthreads();
        }
    }
}

// ---------------------------------------------------------------------------
// proj: out[o][v][s] = bias[o] + sum_{k,f} W[k,f,o] * x_k[f,v,s]
// Block = 64v x 16s tile, 1024 threads, acc[16]/thread.
// R1: single shared buffer (34.8KB) reused x0t -> output staging;
//     5 barriers total (was 33); float4 stage loads + float4 stores;
//     cheb bf16 loads batched per k for memory-level parallelism.
// ---------------------------------------------------------------------------
__global__ __launch_bounds__(TPB)
void proj(const float* __restrict__ in,          // [FIN][V][S]
          const __hip_bfloat16* __restrict__ cheb, // [4][S][FIN][VP]
          const float* __restrict__ W,           // [5][8][16]
          const float* __restrict__ bias,        // [16]
          float* __restrict__ out)               // [FOUT][V][S]
{
    __shared__ float smem[8 * 64 * 17];          // 34816 B, dual-purpose
    const int v0 = blockIdx.x * 64;
    const int s0 = blockIdx.y * 16;
    const int t  = threadIdx.x;

    // stage x0 tile with float4 loads: smem[f*1088 + v*17 + s]
#pragma unroll
    for (int p = 0; p < 2; ++p) {
        const int idx = t + p * TPB;             // 0..2047
        const int sq  = idx & 3;                 // s-quad
        const int v   = (idx >> 2) & 63;
        const int f   = idx >> 8;                // 0..7
        const int vg  = (v0 + v < V_) ? (v0 + v) : (V_ - 1);
        const float4 x = ld4(in + (long)f * VS_ + (long)vg * S_ + s0 + sq * 4);
        float* d = &smem[f * 1088 + v * 17 + sq * 4];
        d[0] = x.x; d[1] = x.y; d[2] = x.z; d[3] = x.w;
    }
    __syncthreads();

    const int tv = t & 63;                       // v within tile (v-fast)
    const int ts = t >> 6;                       // s within tile, 0..15
    const int vg = (v0 + tv < V_) ? (v0 + tv) : (V_ - 1);

    float acc[16];
#pragma unroll
    for (int o = 0; o < 16; ++o) acc[o] = bias[o];

    // k = 0 from LDS (stride-17 rows: conflict-free across 64 lanes)
#pragma unroll
    for (int f = 0; f < FIN_; ++f) {
        const float xv = smem[f * 1088 + tv * 17 + ts];
#pragma unroll
        for (int o = 0; o < 16; ++o)
            acc[o] = fmaf(W[f * 16 + o], xv, acc[o]);
    }
    // k = 1..4 from cheb: batch the 8 bf16 loads per k, then FMA
#pragma unroll
    for (int k = 1; k < 5; ++k) {
        const __hip_bfloat16* cp =
            cheb + ((long)(k - 1) * S_ + (s0 + ts)) * FIN_ * VP_ + vg;
        float xv[8];
#pragma unroll
        for (int f = 0; f < 8; ++f)
            xv[f] = __bfloat162float(cp[(long)f * VP_]);
#pragma unroll
        for (int f = 0; f < 8; ++f) {
#pragma unroll
            for (int o = 0; o < 16; ++o)
                acc[o] = fmaf(W[(k * 8 + f) * 16 + o], xv[f], acc[o]);
        }
    }

    // output: two halves of 8 o; LDS transpose then float4 stores
#pragma unroll
    for (int h = 0; h < 2; ++h) {
        __syncthreads();                         // smem free (x0t / prev half)
#pragma unroll
        for (int ol = 0; ol < 8; ++ol)
            smem[ol * 1088 + tv * 17 + ts] = acc[h * 8 + ol];
        __syncthreads();
#pragma unroll
        for (int p = 0; p < 2; ++p) {
            const int idx = t + p * TPB;         // 0..2047
            const int sq  = idx & 3;
            const int v   = (idx >> 2) & 63;
            const int ol  = idx >> 8;            // 0..7
            if (v0 + v < V_) {
                const float* r = &smem[ol * 1088 + v * 17 + sq * 4];
                st4(out + (long)(h * 8 + ol) * VS_ + (long)(v0 + v) * S_ + s0 + sq * 4,
                    make_float4(r[0], r[1], r[2], r[3]));
            }
        }
    }
}

extern "C" void kernel_launch(void* const* d_in, const int* in_sizes, int n_in,
                              void* d_out, int out_size, void* d_ws, size_t ws_size,
                              hipStream_t stream) {
    const float* in   = (const float*)d_in[0];
    // d_in[1] = lap_rows == repeat(arange(V), DEG) by construction -> implicit
    const int*   cols = (const int*)d_in[2];
    const float* vals = (const float*)d_in[3];
    const float* W    = (const float*)d_in[4];
    const float* bias = (const float*)d_in[5];
    float* out = (float*)d_out;

    // inT (42 MB) borrows d_out's lower half (only read by cheb_rec, which
    // completes before proj overwrites d_out). cheb bf16 (84.0 MB) in d_ws.
    float* inT = out;
    __hip_bfloat16* cheb = (__hip_bfloat16*)d_ws;

    (void)hipFuncSetAttribute((const void*)cheb_rec,
                              hipFuncAttributeMaxDynamicSharedMemorySize,
                              VP_ * LSTR * (int)sizeof(float));

    // T1: in[f][v][s] -> inT[f][s][v]
    transpose_k<<<dim3(8, 41, 8), 256, 0, stream>>>(
        in, inT, V_, S_, (long)VS_, INT_PLANE, VP_);

    // Recursion: emit x1..x4 (bf16) to cheb
    cheb_rec<<<dim3(S_), TPB, VP_ * LSTR * (int)sizeof(float), stream>>>(
        inT, cols, vals, cheb);

    // Projection + transpose: write final out[o][v][s]
    proj<<<dim3(41, 32), TPB, 0, stream>>>(in, cheb, W, bias, out);
}

// Round 3
// 210.416 us; speedup vs baseline: 1.1019x; 1.0525x over previous
//
#include <hip/hip_runtime.h>
#include <hip/hip_bf16.h>

// Problem constants (fixed by reference)
constexpr int V_    = 2562;
constexpr int DEG_  = 8;
constexpr int FIN_  = 8;
constexpr int FOUT_ = 16;
constexpr int S_    = 512;              // X*Y*Z
constexpr int VS_   = V_ * S_;          // elements per f-plane of in/out
constexpr int VP_   = 2564;             // V padded to %4==0 (16B-aligned rows)
constexpr int LSTR  = 12;               // LDS floats per vertex (8 used + 4 pad)
constexpr long INT_PLANE = (long)S_ * VP_;   // floats per f-plane of inT
constexpr int TPB   = 1024;
constexpr int NV    = 3;                // vertices per thread (ceil(2562/1024))

__device__ __forceinline__ float4 ld4(const float* p) {
    return *reinterpret_cast<const float4*>(p);
}
__device__ __forceinline__ void st4(float* p, float4 v) {
    *reinterpret_cast<float4*>(p) = v;
}
__device__ __forceinline__ ushort f2bf_bits(float x) {
    __hip_bfloat16 h = __float2bfloat16(x);
    return *reinterpret_cast<ushort*>(&h);
}
__device__ __forceinline__ float bf2f_bits(ushort u) {
    return __uint_as_float((unsigned)u << 16);
}

// ---------------------------------------------------------------------------
// T1: tiled transpose in[f][v][s] -> inT[f][s][v-padded]
// ---------------------------------------------------------------------------
__global__ __launch_bounds__(256)
void transpose_k(const float* __restrict__ src, float* __restrict__ dst,
                 int M, int N, long srcZ, long dstZ, int dstStride)
{
    __shared__ float tile[64][65];
    const long zs = (long)blockIdx.z * srcZ;
    const long zd = (long)blockIdx.z * dstZ;
    const int n0 = blockIdx.x * 64;
    const int m0 = blockIdx.y * 64;
    const int t  = threadIdx.x;
    const int q  = t & 15;
    const int r  = t >> 4;

#pragma unroll
    for (int i = 0; i < 4; ++i) {
        const int m = m0 + r + i * 16;
        const int n = n0 + q * 4;
        if (m < M && n < N) {
            const float4 x = ld4(src + zs + (long)m * N + n);
            tile[r + i * 16][q * 4 + 0] = x.x;
            tile[r + i * 16][q * 4 + 1] = x.y;
            tile[r + i * 16][q * 4 + 2] = x.z;
            tile[r + i * 16][q * 4 + 3] = x.w;
        }
    }
    __syncthreads();
#pragma unroll
    for (int i = 0; i < 4; ++i) {
        const int n = n0 + r + i * 16;
        const int m = m0 + q * 4;
        if (n < N && (m + 4) <= dstStride) {
            const float4 x = make_float4(tile[q * 4 + 0][r + i * 16],
                                         tile[q * 4 + 1][r + i * 16],
                                         tile[q * 4 + 2][r + i * 16],
                                         tile[q * 4 + 3][r + i * 16]);
            st4(dst + zd + (long)n * dstStride + m, x);
        }
    }
}

// ---------------------------------------------------------------------------
// cheb_rec: per s-slice, run the K=5 recursion in LDS (fp32) and emit
// x1..x4 as bf16 to cheb[(k-1)][s][v][f] (f-fast: one 16B store per vertex).
// ---------------------------------------------------------------------------
__global__ __launch_bounds__(TPB)
void cheb_rec(const float* __restrict__ inT,   // [FIN][S][VP]
              const int*   __restrict__ cols,  // [V][8]
              const float* __restrict__ vals,  // [V][8]
              ushort* __restrict__ cheb)       // [4][S][V][8] bf16 bits
{
    extern __shared__ float cur[];              // VP_*LSTR floats = 123072 B
    const int s = blockIdx.x;
    const int t = threadIdx.x;

    // fill cur[v*12 + f] = inT[f][s][v]
    {
        const int f = t & 7;
        const int cb = t >> 3;
        const float* plane = inT + (long)f * INT_PLANE + (long)s * VP_;
        for (int c = cb; c < VP_ / 4; c += TPB / 8) {
            const float4 x = ld4(plane + c * 4);
            cur[(c * 4 + 0) * LSTR + f] = x.x;
            cur[(c * 4 + 1) * LSTR + f] = x.y;
            cur[(c * 4 + 2) * LSTR + f] = x.z;
            cur[(c * 4 + 3) * LSTR + f] = x.w;
        }
    }
    __syncthreads();

    float xp[NV][8];        // x_{k-2} at own vertices (starts as x0)
#pragma unroll
    for (int j = 0; j < NV; ++j) {
        const int v = (t + j * TPB < V_) ? (t + j * TPB) : 0;
        const float4 lo = ld4(&cur[v * LSTR]);
        const float4 hi = ld4(&cur[v * LSTR + 4]);
        xp[j][0] = lo.x; xp[j][1] = lo.y; xp[j][2] = lo.z; xp[j][3] = lo.w;
        xp[j][4] = hi.x; xp[j][5] = hi.y; xp[j][6] = hi.z; xp[j][7] = hi.w;
    }

#pragma unroll 1
    for (int k = 1; k < 5; ++k) {
        float xk[NV][8];
#pragma unroll
        for (int j = 0; j < NV; ++j) {
            const bool valid = (t + j * TPB) < V_;
            const int v = valid ? (t + j * TPB) : 0;
            int off = v * 8;
            asm volatile("" : "+v"(off));       // block LICM of k-invariant loads
            const int4   ca = *reinterpret_cast<const int4*>(cols + off);
            const int4   cb = *reinterpret_cast<const int4*>(cols + off + 4);
            const float4 wa = ld4(vals + off);
            const float4 wb = ld4(vals + off + 4);
            const int   cc[8] = {ca.x, ca.y, ca.z, ca.w, cb.x, cb.y, cb.z, cb.w};
            const float ww[8] = {wa.x, wa.y, wa.z, wa.w, wb.x, wb.y, wb.z, wb.w};

            float a[8];
#pragma unroll
            for (int e = 0; e < 8; ++e) a[e] = 0.f;
#pragma unroll
            for (int n = 0; n < 8; ++n) {
                const float* p = &cur[cc[n] * LSTR];
                const float4 lo = ld4(p);
                const float4 hi = ld4(p + 4);
                const float w = ww[n];
                a[0] = fmaf(w, lo.x, a[0]); a[1] = fmaf(w, lo.y, a[1]);
                a[2] = fmaf(w, lo.z, a[2]); a[3] = fmaf(w, lo.w, a[3]);
                a[4] = fmaf(w, hi.x, a[4]); a[5] = fmaf(w, hi.y, a[5]);
                a[6] = fmaf(w, hi.z, a[6]); a[7] = fmaf(w, hi.w, a[7]);
            }
#pragma unroll
            for (int e = 0; e < 8; ++e)
                xk[j][e] = (k == 1) ? a[e] : fmaf(2.f, a[e], -xp[j][e]);

            // emit bf16 row [v][0..8) as one 16B store (lanes: consecutive v)
            if (valid) {
                union { ushort u[8]; int4 q; } pk;
#pragma unroll
                for (int f = 0; f < 8; ++f)
                    pk.u[f] = f2bf_bits(xk[j][f]);
                *reinterpret_cast<int4*>(
                    cheb + (((long)(k - 1) * S_ + s) * V_ + v) * 8) = pk.q;
            }

            // stage next xprev = x_{k-1}[own] (cur is stable until the barrier)
            if (k < 4) {
                const float4 lo = ld4(&cur[v * LSTR]);
                const float4 hi = ld4(&cur[v * LSTR + 4]);
                xp[j][0] = lo.x; xp[j][1] = lo.y; xp[j][2] = lo.z; xp[j][3] = lo.w;
                xp[j][4] = hi.x; xp[j][5] = hi.y; xp[j][6] = hi.z; xp[j][7] = hi.w;
            }
        }
        if (k < 4) {
            __syncthreads();
#pragma unroll
            for (int j = 0; j < NV; ++j) {
                const int vr = t + j * TPB;
                if (vr < V_) {
                    st4(&cur[vr * LSTR],
                        make_float4(xk[j][0], xk[j][1], xk[j][2], xk[j][3]));
                    st4(&cur[vr * LSTR + 4],
                        make_float4(xk[j][4], xk[j][5], xk[j][6], xk[j][7]));
                }
            }
            __syncthreads();
        }
    }
}

// ---------------------------------------------------------------------------
// proj: out[o][v][s] = bias[o] + sum_{k,f} W[k,f,o] * x_k[f,v,s]
// Block = 64v x 16s tile, 1024 threads, acc[16]/thread.
// R2: cheb is f-fast -> one dwordx4 load per k (was 8 scalar ushort).
// ---------------------------------------------------------------------------
__global__ __launch_bounds__(TPB)
void proj(const float* __restrict__ in,          // [FIN][V][S]
          const ushort* __restrict__ cheb,       // [4][S][V][8] bf16 bits
          const float* __restrict__ W,           // [5][8][16]
          const float* __restrict__ bias,        // [16]
          float* __restrict__ out)               // [FOUT][V][S]
{
    __shared__ float smem[8 * 64 * 17];          // 34816 B, dual-purpose
    const int v0 = blockIdx.x * 64;
    const int s0 = blockIdx.y * 16;
    const int t  = threadIdx.x;

    // stage x0 tile with float4 loads: smem[f*1088 + v*17 + s]
#pragma unroll
    for (int p = 0; p < 2; ++p) {
        const int idx = t + p * TPB;             // 0..2047
        const int sq  = idx & 3;                 // s-quad
        const int v   = (idx >> 2) & 63;
        const int f   = idx >> 8;                // 0..7
        const int vg  = (v0 + v < V_) ? (v0 + v) : (V_ - 1);
        const float4 x = ld4(in + (long)f * VS_ + (long)vg * S_ + s0 + sq * 4);
        float* d = &smem[f * 1088 + v * 17 + sq * 4];
        d[0] = x.x; d[1] = x.y; d[2] = x.z; d[3] = x.w;
    }
    __syncthreads();

    const int tv = t & 63;                       // v within tile (v-fast)
    const int ts = t >> 6;                       // s within tile, 0..15
    const int vg = (v0 + tv < V_) ? (v0 + tv) : (V_ - 1);

    float acc[16];
#pragma unroll
    for (int o = 0; o < 16; ++o) acc[o] = bias[o];

    // k = 0 from LDS (stride-17 rows: conflict-free across 64 lanes)
#pragma unroll
    for (int f = 0; f < FIN_; ++f) {
        const float xv = smem[f * 1088 + tv * 17 + ts];
#pragma unroll
        for (int o = 0; o < 16; ++o)
            acc[o] = fmaf(W[f * 16 + o], xv, acc[o]);
    }
    // k = 1..4 from cheb: one 16B load per k (8 bf16, f-fast)
#pragma unroll
    for (int k = 1; k < 5; ++k) {
        union { int4 q; ushort u[8]; } pk;
        pk.q = *reinterpret_cast<const int4*>(
            cheb + (((long)(k - 1) * S_ + (s0 + ts)) * V_ + vg) * 8);
        float xv[8];
#pragma unroll
        for (int f = 0; f < 8; ++f)
            xv[f] = bf2f_bits(pk.u[f]);
#pragma unroll
        for (int f = 0; f < 8; ++f) {
#pragma unroll
            for (int o = 0; o < 16; ++o)
                acc[o] = fmaf(W[(k * 8 + f) * 16 + o], xv[f], acc[o]);
        }
    }

    // output: two halves of 8 o; LDS transpose then float4 stores
#pragma unroll
    for (int h = 0; h < 2; ++h) {
        __syncthreads();                         // smem free (x0t / prev half)
#pragma unroll
        for (int ol = 0; ol < 8; ++ol)
            smem[ol * 1088 + tv * 17 + ts] = acc[h * 8 + ol];
        __syncthreads();
#pragma unroll
        for (int p = 0; p < 2; ++p) {
            const int idx = t + p * TPB;         // 0..2047
            const int sq  = idx & 3;
            const int v   = (idx >> 2) & 63;
            const int ol  = idx >> 8;            // 0..7
            if (v0 + v < V_) {
                const float* r = &smem[ol * 1088 + v * 17 + sq * 4];
                st4(out + (long)(h * 8 + ol) * VS_ + (long)(v0 + v) * S_ + s0 + sq * 4,
                    make_float4(r[0], r[1], r[2], r[3]));
            }
        }
    }
}

extern "C" void kernel_launch(void* const* d_in, const int* in_sizes, int n_in,
                              void* d_out, int out_size, void* d_ws, size_t ws_size,
                              hipStream_t stream) {
    const float* in   = (const float*)d_in[0];
    // d_in[1] = lap_rows == repeat(arange(V), DEG) by construction -> implicit
    const int*   cols = (const int*)d_in[2];
    const float* vals = (const float*)d_in[3];
    const float* W    = (const float*)d_in[4];
    const float* bias = (const float*)d_in[5];
    float* out = (float*)d_out;

    // inT (42 MB) borrows d_out's lower half (only read by cheb_rec, which
    // completes before proj overwrites d_out). cheb bf16 (84.0 MB) in d_ws.
    float* inT = out;
    ushort* cheb = (ushort*)d_ws;

    (void)hipFuncSetAttribute((const void*)cheb_rec,
                              hipFuncAttributeMaxDynamicSharedMemorySize,
                              VP_ * LSTR * (int)sizeof(float));

    // T1: in[f][v][s] -> inT[f][s][v]
    transpose_k<<<dim3(8, 41, 8), 256, 0, stream>>>(
        in, inT, V_, S_, (long)VS_, INT_PLANE, VP_);

    // Recursion: emit x1..x4 (bf16) to cheb
    cheb_rec<<<dim3(S_), TPB, VP_ * LSTR * (int)sizeof(float), stream>>>(
        inT, cols, vals, cheb);

    // Projection + transpose: write final out[o][v][s]
    proj<<<dim3(41, 32), TPB, 0, stream>>>(in, cheb, W, bias, out);
}

// Round 4
// 196.773 us; speedup vs baseline: 1.1783x; 1.0693x over previous
//
#include <hip/hip_runtime.h>
#include <hip/hip_bf16.h>
#include <hip/hip_fp16.h>

// Problem constants (fixed by reference)
constexpr int V_    = 2562;
constexpr int DEG_  = 8;
constexpr int FIN_  = 8;
constexpr int FOUT_ = 16;
constexpr int S_    = 512;              // X*Y*Z
constexpr int VS_   = V_ * S_;          // elements per f-plane of in/out
constexpr int VP_   = 2564;             // V padded to %4==0 (16B-aligned rows)
constexpr int LSTR  = 12;               // LDS dwords per vertex (8 used + 4 pad)
constexpr long INT_PLANE = (long)S_ * VP_;   // floats per f-plane of inT
constexpr int TPB   = 1024;
constexpr int NV    = 3;                // vertices per thread (ceil(2562/1024))

__device__ __forceinline__ float4 ld4(const float* p) {
    return *reinterpret_cast<const float4*>(p);
}
__device__ __forceinline__ void st4(float* p, float4 v) {
    *reinterpret_cast<float4*>(p) = v;
}
__device__ __forceinline__ unsigned h2bits(__half2 h) {
    union { __half2 h; unsigned u; } c; c.h = h; return c.u;
}
__device__ __forceinline__ __half2 bits2h(unsigned u) {
    union { unsigned u; __half2 h; } c; c.u = u; return c.h;
}
__device__ __forceinline__ unsigned packh2(float e, float o) {
    return h2bits(__halves2half2(__float2half(e), __float2half(o)));
}

// ---------------------------------------------------------------------------
// T1: tiled transpose in[f][v][s] -> inT[f][s][v-padded]
// ---------------------------------------------------------------------------
__global__ __launch_bounds__(256)
void transpose_k(const float* __restrict__ src, float* __restrict__ dst,
                 int M, int N, long srcZ, long dstZ, int dstStride)
{
    __shared__ float tile[64][65];
    const long zs = (long)blockIdx.z * srcZ;
    const long zd = (long)blockIdx.z * dstZ;
    const int n0 = blockIdx.x * 64;
    const int m0 = blockIdx.y * 64;
    const int t  = threadIdx.x;
    const int q  = t & 15;
    const int r  = t >> 4;

#pragma unroll
    for (int i = 0; i < 4; ++i) {
        const int m = m0 + r + i * 16;
        const int n = n0 + q * 4;
        if (m < M && n < N) {
            const float4 x = ld4(src + zs + (long)m * N + n);
            tile[r + i * 16][q * 4 + 0] = x.x;
            tile[r + i * 16][q * 4 + 1] = x.y;
            tile[r + i * 16][q * 4 + 2] = x.z;
            tile[r + i * 16][q * 4 + 3] = x.w;
        }
    }
    __syncthreads();
#pragma unroll
    for (int i = 0; i < 4; ++i) {
        const int n = n0 + r + i * 16;
        const int m = m0 + q * 4;
        if (n < N && (m + 4) <= dstStride) {
            const float4 x = make_float4(tile[q * 4 + 0][r + i * 16],
                                         tile[q * 4 + 1][r + i * 16],
                                         tile[q * 4 + 2][r + i * 16],
                                         tile[q * 4 + 3][r + i * 16]);
            st4(dst + zd + (long)n * dstStride + m, x);
        }
    }
}

// ---------------------------------------------------------------------------
// cheb_rec: TWO s-slices per block, state packed f16x2 in LDS.
// Each ds_read_b128 / v_pk_fma_f16 serves both slices -> per-slice DS and
// VALU halved vs fp32-scalar version. Emits x1..x4 as f16 to
// cheb[(k-1)][s][v][f] via v_perm extraction (one 16B store per slice).
// ---------------------------------------------------------------------------
__global__ __launch_bounds__(TPB)
void cheb_rec(const float* __restrict__ inT,   // [FIN][S][VP] fp32
              const int*   __restrict__ cols,  // [V][8]
              const float* __restrict__ vals,  // [V][8]
              ushort* __restrict__ cheb)       // [4][S][V][8] f16 bits
{
    extern __shared__ unsigned cur[];           // VP_*LSTR dwords = 123072 B
    const int s2 = blockIdx.x * 2;              // even slice; odd = s2+1
    const int t  = threadIdx.x;

    // fill cur[v*12 + f] = half2(inT[f][s2][v], inT[f][s2+1][v])
    {
        const int f  = t & 7;
        const int cb = t >> 3;
        const float* pe = inT + (long)f * INT_PLANE + (long)s2 * VP_;
        const float* po = pe + VP_;
        for (int c = cb; c < VP_ / 4; c += TPB / 8) {
            const float4 xe = ld4(pe + c * 4);
            const float4 xo = ld4(po + c * 4);
            cur[(c * 4 + 0) * LSTR + f] = packh2(xe.x, xo.x);
            cur[(c * 4 + 1) * LSTR + f] = packh2(xe.y, xo.y);
            cur[(c * 4 + 2) * LSTR + f] = packh2(xe.z, xo.z);
            cur[(c * 4 + 3) * LSTR + f] = packh2(xe.w, xo.w);
        }
    }
    __syncthreads();

    const __half2 two2 = __half2half2(__float2half(2.0f));

    __half2 xp[NV][8];      // x_{k-2} at own vertices (starts as x0)
#pragma unroll
    for (int j = 0; j < NV; ++j) {
        const int v = (t + j * TPB < V_) ? (t + j * TPB) : 0;
        const uint4 lo = *reinterpret_cast<const uint4*>(&cur[v * LSTR]);
        const uint4 hi = *reinterpret_cast<const uint4*>(&cur[v * LSTR + 4]);
        xp[j][0] = bits2h(lo.x); xp[j][1] = bits2h(lo.y);
        xp[j][2] = bits2h(lo.z); xp[j][3] = bits2h(lo.w);
        xp[j][4] = bits2h(hi.x); xp[j][5] = bits2h(hi.y);
        xp[j][6] = bits2h(hi.z); xp[j][7] = bits2h(hi.w);
    }

#pragma unroll 1
    for (int k = 1; k < 5; ++k) {
        __half2 xk[NV][8];
#pragma unroll
        for (int j = 0; j < NV; ++j) {
            const bool valid = (t + j * TPB) < V_;
            const int v = valid ? (t + j * TPB) : 0;
            int off = v * 8;
            asm volatile("" : "+v"(off));       // block LICM of k-invariant loads
            const int4   ca = *reinterpret_cast<const int4*>(cols + off);
            const int4   cb = *reinterpret_cast<const int4*>(cols + off + 4);
            const float4 wa = ld4(vals + off);
            const float4 wb = ld4(vals + off + 4);
            const int   cc[8] = {ca.x, ca.y, ca.z, ca.w, cb.x, cb.y, cb.z, cb.w};
            const float ww[8] = {wa.x, wa.y, wa.z, wa.w, wb.x, wb.y, wb.z, wb.w};

            __half2 a[8];
#pragma unroll
            for (int e = 0; e < 8; ++e) a[e] = bits2h(0u);
#pragma unroll
            for (int n = 0; n < 8; ++n) {
                const unsigned* p = &cur[cc[n] * LSTR];
                const uint4 lo = *reinterpret_cast<const uint4*>(p);
                const uint4 hi = *reinterpret_cast<const uint4*>(p + 4);
                const __half2 w2 = __half2half2(__float2half(ww[n]));
                a[0] = __hfma2(w2, bits2h(lo.x), a[0]);
                a[1] = __hfma2(w2, bits2h(lo.y), a[1]);
                a[2] = __hfma2(w2, bits2h(lo.z), a[2]);
                a[3] = __hfma2(w2, bits2h(lo.w), a[3]);
                a[4] = __hfma2(w2, bits2h(hi.x), a[4]);
                a[5] = __hfma2(w2, bits2h(hi.y), a[5]);
                a[6] = __hfma2(w2, bits2h(hi.z), a[6]);
                a[7] = __hfma2(w2, bits2h(hi.w), a[7]);
            }
#pragma unroll
            for (int e = 0; e < 8; ++e)
                xk[j][e] = (k == 1) ? a[e]
                                    : __hfma2(two2, a[e], __hneg2(xp[j][e]));

            // emit both slices: v_perm extracts lo/hi f16 halves into dwords
            if (valid) {
                unsigned ue[4], uo[4];
#pragma unroll
                for (int i = 0; i < 4; ++i) {
                    const unsigned b0 = h2bits(xk[j][2 * i]);
                    const unsigned b1 = h2bits(xk[j][2 * i + 1]);
                    ue[i] = __builtin_amdgcn_perm(b1, b0, 0x05040100u); // even s
                    uo[i] = __builtin_amdgcn_perm(b1, b0, 0x07060302u); // odd  s
                }
                const long base = (((long)(k - 1) * S_ + s2) * V_ + v) * 8;
                *reinterpret_cast<uint4*>(cheb + base) =
                    make_uint4(ue[0], ue[1], ue[2], ue[3]);
                *reinterpret_cast<uint4*>(cheb + base + (long)V_ * 8) =
                    make_uint4(uo[0], uo[1], uo[2], uo[3]);
            }

            // stage next xprev = x_{k-1}[own] (cur stable until the barrier)
            if (k < 4) {
                const uint4 lo = *reinterpret_cast<const uint4*>(&cur[v * LSTR]);
                const uint4 hi = *reinterpret_cast<const uint4*>(&cur[v * LSTR + 4]);
                xp[j][0] = bits2h(lo.x); xp[j][1] = bits2h(lo.y);
                xp[j][2] = bits2h(lo.z); xp[j][3] = bits2h(lo.w);
                xp[j][4] = bits2h(hi.x); xp[j][5] = bits2h(hi.y);
                xp[j][6] = bits2h(hi.z); xp[j][7] = bits2h(hi.w);
            }
        }
        if (k < 4) {
            __syncthreads();
#pragma unroll
            for (int j = 0; j < NV; ++j) {
                const int vr = t + j * TPB;
                if (vr < V_) {
                    *reinterpret_cast<uint4*>(&cur[vr * LSTR]) =
                        make_uint4(h2bits(xk[j][0]), h2bits(xk[j][1]),
                                   h2bits(xk[j][2]), h2bits(xk[j][3]));
                    *reinterpret_cast<uint4*>(&cur[vr * LSTR + 4]) =
                        make_uint4(h2bits(xk[j][4]), h2bits(xk[j][5]),
                                   h2bits(xk[j][6]), h2bits(xk[j][7]));
                }
            }
            __syncthreads();
        }
    }
}

// ---------------------------------------------------------------------------
// proj: out[o][v][s] = bias[o] + sum_{k,f} W[k,f,o] * x_k[f,v,s]
// Block = 64v x 16s tile, 1024 threads, acc[16]/thread.
// cheb is f16, f-fast -> one dwordx4 load per k.
// ---------------------------------------------------------------------------
__global__ __launch_bounds__(TPB)
void proj(const float* __restrict__ in,          // [FIN][V][S]
          const ushort* __restrict__ cheb,       // [4][S][V][8] f16 bits
          const float* __restrict__ W,           // [5][8][16]
          const float* __restrict__ bias,        // [16]
          float* __restrict__ out)               // [FOUT][V][S]
{
    __shared__ float smem[8 * 64 * 17];          // 34816 B, dual-purpose
    const int v0 = blockIdx.x * 64;
    const int s0 = blockIdx.y * 16;
    const int t  = threadIdx.x;

    // stage x0 tile with float4 loads: smem[f*1088 + v*17 + s]
#pragma unroll
    for (int p = 0; p < 2; ++p) {
        const int idx = t + p * TPB;             // 0..2047
        const int sq  = idx & 3;                 // s-quad
        const int v   = (idx >> 2) & 63;
        const int f   = idx >> 8;                // 0..7
        const int vg  = (v0 + v < V_) ? (v0 + v) : (V_ - 1);
        const float4 x = ld4(in + (long)f * VS_ + (long)vg * S_ + s0 + sq * 4);
        float* d = &smem[f * 1088 + v * 17 + sq * 4];
        d[0] = x.x; d[1] = x.y; d[2] = x.z; d[3] = x.w;
    }
    __syncthreads();

    const int tv = t & 63;                       // v within tile (v-fast)
    const int ts = t >> 6;                       // s within tile, 0..15
    const int vg = (v0 + tv < V_) ? (v0 + tv) : (V_ - 1);

    float acc[16];
#pragma unroll
    for (int o = 0; o < 16; ++o) acc[o] = bias[o];

    // k = 0 from LDS (stride-17 rows: conflict-free across 64 lanes)
#pragma unroll
    for (int f = 0; f < FIN_; ++f) {
        const float xv = smem[f * 1088 + tv * 17 + ts];
#pragma unroll
        for (int o = 0; o < 16; ++o)
            acc[o] = fmaf(W[f * 16 + o], xv, acc[o]);
    }
    // k = 1..4 from cheb: one 16B load per k (8 f16, f-fast)
#pragma unroll
    for (int k = 1; k < 5; ++k) {
        union { int4 q; __half u[8]; } pk;
        pk.q = *reinterpret_cast<const int4*>(
            cheb + (((long)(k - 1) * S_ + (s0 + ts)) * V_ + vg) * 8);
        float xv[8];
#pragma unroll
        for (int f = 0; f < 8; ++f)
            xv[f] = __half2float(pk.u[f]);
#pragma unroll
        for (int f = 0; f < 8; ++f) {
#pragma unroll
            for (int o = 0; o < 16; ++o)
                acc[o] = fmaf(W[(k * 8 + f) * 16 + o], xv[f], acc[o]);
        }
    }

    // output: two halves of 8 o; LDS transpose then float4 stores
#pragma unroll
    for (int h = 0; h < 2; ++h) {
        __syncthreads();                         // smem free (x0t / prev half)
#pragma unroll
        for (int ol = 0; ol < 8; ++ol)
            smem[ol * 1088 + tv * 17 + ts] = acc[h * 8 + ol];
        __syncthreads();
#pragma unroll
        for (int p = 0; p < 2; ++p) {
            const int idx = t + p * TPB;         // 0..2047
            const int sq  = idx & 3;
            const int v   = (idx >> 2) & 63;
            const int ol  = idx >> 8;            // 0..7
            if (v0 + v < V_) {
                const float* r = &smem[ol * 1088 + v * 17 + sq * 4];
                st4(out + (long)(h * 8 + ol) * VS_ + (long)(v0 + v) * S_ + s0 + sq * 4,
                    make_float4(r[0], r[1], r[2], r[3]));
            }
        }
    }
}

extern "C" void kernel_launch(void* const* d_in, const int* in_sizes, int n_in,
                              void* d_out, int out_size, void* d_ws, size_t ws_size,
                              hipStream_t stream) {
    const float* in   = (const float*)d_in[0];
    // d_in[1] = lap_rows == repeat(arange(V), DEG) by construction -> implicit
    const int*   cols = (const int*)d_in[2];
    const float* vals = (const float*)d_in[3];
    const float* W    = (const float*)d_in[4];
    const float* bias = (const float*)d_in[5];
    float* out = (float*)d_out;

    // inT (42 MB) borrows d_out's lower half (only read by cheb_rec, which
    // completes before proj overwrites d_out). cheb f16 (84.0 MB) in d_ws.
    float* inT = out;
    ushort* cheb = (ushort*)d_ws;

    (void)hipFuncSetAttribute((const void*)cheb_rec,
                              hipFuncAttributeMaxDynamicSharedMemorySize,
                              VP_ * LSTR * (int)sizeof(unsigned));

    // T1: in[f][v][s] -> inT[f][s][v]
    transpose_k<<<dim3(8, 41, 8), 256, 0, stream>>>(
        in, inT, V_, S_, (long)VS_, INT_PLANE, VP_);

    // Recursion: 2 s-slices per block, emit x1..x4 (f16) to cheb
    cheb_rec<<<dim3(S_ / 2), TPB, VP_ * LSTR * (int)sizeof(unsigned), stream>>>(
        inT, cols, vals, cheb);

    // Projection + transpose: write final out[o][v][s]
    proj<<<dim3(41, 32), TPB, 0, stream>>>(in, cheb, W, bias, out);
}